// Round 19
// baseline (46.986 us; speedup 1.0000x reference)
//
#include <hip/hip_runtime.h>

#define K7   7
#define PAD3 3
#define C64  64
#define CRED 32          // C/2
#define GC4  4
#define EPSV 1e-5f

#define TILE 8                      // 8x8 pixels per block (k2 / fused)
#define HALO 14                     // TILE + K7 - 1
#define NPIX (HALO * HALO)          // 196

typedef _Float16 half8 __attribute__((ext_vector_type(8)));
typedef _Float16 half4 __attribute__((ext_vector_type(4)));
typedef float    f32x4 __attribute__((ext_vector_type(4)));

// ============================= two-kernel path =============================
// ---- kernel 1: conv1 (1x1) + BN(eval) + ReLU -> t[b][pix][32] as f16 ----
__global__ __launch_bounds__(256, 4)
void conv1_bn_relu(const float* __restrict__ x,  const float* __restrict__ w1,
                   const float* __restrict__ b1, const float* __restrict__ gma,
                   const float* __restrict__ bta, const float* __restrict__ mu,
                   const float* __restrict__ var, _Float16* __restrict__ t)
{
    const int tid = threadIdx.x;
    const int p   = tid & 63;
    const int oq  = __builtin_amdgcn_readfirstlane(tid >> 6);
    const int task = blockIdx.x * 64 + p;           // 0 .. 65535
    const int b   = task >> 14;
    const int pix = task & 16383;

    float dot[8] = {0,0,0,0,0,0,0,0};
    const float* w1q = w1 + oq * 8 * C64;
    const float* xp  = x + ((size_t)b << 20) + pix;
    #pragma unroll 8
    for (int c = 0; c < C64; ++c) {
        float xc = xp[(size_t)c << 14];
        #pragma unroll
        for (int j = 0; j < 8; ++j) dot[j] += w1q[j * C64 + c] * xc;
    }
    _Float16 tv[8];
    #pragma unroll
    for (int j = 0; j < 8; ++j) {
        int o = oq * 8 + j;
        float sv = gma[o] * rsqrtf(var[o] + EPSV);
        float bb = (b1[o] - mu[o]) * sv + bta[o];
        tv[j] = (_Float16)fmaxf(dot[j] * sv + bb, 0.f);
    }
    *(half8*)&t[((size_t)((b << 14) + pix)) * 32 + oq * 8] = *(const half8*)tv;
}

// ---- kernel 2: per-pixel dynamic kernels (MFMA) + depthwise aggregation ----
// Round-16 structure (best measured): quarter-channel blocks, 1 group/wave,
// PER-WAVE staging of ytile slice AND w2 group, NO block barrier.
// This round: YPS 20->18, W2ST 40->36 (LDS 23.5->21.2 KB -> 7 blocks/CU),
// s_setprio(1) around MFMA clusters (independent waves = attn-like regime).
#define NCH2 16                     // y-channels per block (quarter of 64)
#define NSL2 4                      // channel-groups per block (1 per wave)
#define YPS  18                     // ytile per-pixel stride in f16 (36B)
#define W2ST 36                     // w2h row stride in f16 (72B)
#define W2G  (49 * W2ST)            // 1764 f16 per group

__global__ __launch_bounds__(256, 4)
void invol_agg(const float* __restrict__ y, const _Float16* __restrict__ t,
               const float* __restrict__ w2, const float* __restrict__ b2,
               float* __restrict__ out)
{
    __shared__ __align__(16) _Float16 ytile[NPIX * YPS];   //  7056 B
    __shared__ __align__(16) _Float16 w2h[NSL2 * W2G];     // 14112 B

    const int tid = threadIdx.x;
    // XCD-aware swizzle: 4096 blocks -> 8 chunks of 512 contiguous tiles
    const int wgid = blockIdx.x + (blockIdx.y << 4) + (blockIdx.z << 8);
    const int swz  = ((wgid & 7) << 9) | (wgid >> 3);
    const int bx = swz & 15, by = (swz >> 4) & 15, bz = swz >> 8;
    const int b = bz >> 2, quarter = bz & 3;
    const int gh0 = by * TILE, gw0 = bx * TILE;
    const int c0 = quarter * NCH2;

    const int p  = tid & 63;
    const int ph = p >> 3, pw = p & 7;
    const int oq = __builtin_amdgcn_readfirstlane(tid >> 6);  // wave = group 0..3
    const int q  = p >> 4, r = p & 15;
    const int pix = ((gh0 + ph) << 7) + (gw0 + pw);

    const int g = quarter * NSL2 + oq;         // global group 0..15

    // --- issue B-fragment loads EARLY: latency hides under staging ---
    const _Float16* tb = t + ((size_t)(b << 14)) * 32;
    const int rr8 = r >> 3, rc = r & 7;
    half8 bfrag0 = *(const half8*)&tb[(size_t)(((gh0 + 0 + rr8) << 7) + gw0 + rc) * 32 + q * 8];
    half8 bfrag1 = *(const half8*)&tb[(size_t)(((gh0 + 2 + rr8) << 7) + gw0 + rc) * 32 + q * 8];
    half8 bfrag2 = *(const half8*)&tb[(size_t)(((gh0 + 4 + rr8) << 7) + gw0 + rc) * 32 + q * 8];
    half8 bfrag3 = *(const half8*)&tb[(size_t)(((gh0 + 6 + rr8) << 7) + gw0 + rc) * 32 + q * 8];

    // --- per-wave y halo staging: wave oq stages ONLY its 4 channels ---
    #pragma unroll
    for (int i = 0; i < 4; ++i) {
        int pixl = p + i * 64;                 // 0..195
        if (pixl < NPIX) {
            int rr   = pixl / HALO;
            int col  = pixl - rr * HALO;
            int grow = gh0 - PAD3 + rr;
            int gcol = gw0 - PAD3 + col;
            half4 v = {(_Float16)0.f, (_Float16)0.f, (_Float16)0.f, (_Float16)0.f};
            if ((unsigned)grow < 128u && (unsigned)gcol < 128u) {
                const float* yp = y + ((size_t)(b * C64 + c0 + oq * 4) << 14) + (grow << 7) + gcol;
                v[0] = (_Float16)yp[0];
                v[1] = (_Float16)yp[1 << 14];
                v[2] = (_Float16)yp[2 << 14];
                v[3] = (_Float16)yp[3 << 14];
            }
            *(half4*)&ytile[pixl * YPS + oq * 4] = v;
        }
    }

    // --- per-wave w2 staging: wave oq stages ONLY its group ---
    #pragma unroll
    for (int i = 0; i < 7; ++i) {
        int u = p + i * 64;                    // 0..391 (49 rows x 8 half4-units)
        if (u < 392) {
            int row = u >> 3;
            int k4  = (u & 7) << 2;
            const float4 w4 = *(const float4*)&w2[((g * 49 + row) << 5) + k4];
            half4 h;
            h[0] = (_Float16)w4.x; h[1] = (_Float16)w4.y;
            h[2] = (_Float16)w4.z; h[3] = (_Float16)w4.w;
            *(half4*)&w2h[oq * W2G + row * W2ST + k4] = h;
        }
    }
    // NO __syncthreads(): each wave reads only what it wrote; the compiler's
    // lgkmcnt wait before the first dependent ds_read is the only sync needed.

    // per-lane f16-index bases into ytile: tp2*YPS + oq*4
    const int pbF0 = ((0 + rr8) * HALO + rc) * YPS + oq * 4;
    const int pbF1 = ((2 + rr8) * HALO + rc) * YPS + oq * 4;
    const int pbF2 = ((4 + rr8) * HALO + rc) * YPS + oq * 4;
    const int pbF3 = ((6 + rr8) * HALO + rc) * YPS + oq * 4;

    const f32x4 zero = {0.f, 0.f, 0.f, 0.f};

    const float* b2g = b2 + g * 49;
    const _Float16* w2hg = w2h + oq * W2G;     // wave-uniform base

    float acc[4][4];
    #pragma unroll
    for (int nt = 0; nt < 4; ++nt)
        #pragma unroll
        for (int c = 0; c < 4; ++c) acc[nt][c] = 0.f;

    // mt = 0..2 : rolled (liveness cap); A-frag from LDS, bias as C-init
    #pragma clang loop unroll(disable)
    for (int mt = 0; mt < 3; ++mt) {
        const half8 af = *(const half8*)&w2hg[(mt * 16 + r) * W2ST + q * 8];
        const int bi = mt * 16 + q * 4;
        const f32x4 cb = { b2g[bi+0], b2g[bi+1], b2g[bi+2], b2g[bi+3] };

        __builtin_amdgcn_s_setprio(1);
        f32x4 d0 = __builtin_amdgcn_mfma_f32_16x16x32_f16(af, bfrag0, cb, 0, 0, 0);
        f32x4 d1 = __builtin_amdgcn_mfma_f32_16x16x32_f16(af, bfrag1, cb, 0, 0, 0);
        f32x4 d2 = __builtin_amdgcn_mfma_f32_16x16x32_f16(af, bfrag2, cb, 0, 0, 0);
        f32x4 d3 = __builtin_amdgcn_mfma_f32_16x16x32_f16(af, bfrag3, cb, 0, 0, 0);
        __builtin_amdgcn_s_setprio(0);

        #pragma unroll
        for (int reg = 0; reg < 4; ++reg) {          // MUST stay fully unrolled
            const int tap = mt * 16 + q * 4 + reg;   // lane's tap, < 49
            const int di = (tap * 9363) >> 16;       // tap / 7
            const int toffF = (tap + 7 * di) * YPS;  // (di*14 + dj) * YPS
            {
                const float wv = d0[reg];
                const half4 y4 = *(const half4*)&ytile[pbF0 + toffF];
                acc[0][0] += (float)y4[0] * wv; acc[0][1] += (float)y4[1] * wv;
                acc[0][2] += (float)y4[2] * wv; acc[0][3] += (float)y4[3] * wv;
            }
            {
                const float wv = d1[reg];
                const half4 y4 = *(const half4*)&ytile[pbF1 + toffF];
                acc[1][0] += (float)y4[0] * wv; acc[1][1] += (float)y4[1] * wv;
                acc[1][2] += (float)y4[2] * wv; acc[1][3] += (float)y4[3] * wv;
            }
            {
                const float wv = d2[reg];
                const half4 y4 = *(const half4*)&ytile[pbF2 + toffF];
                acc[2][0] += (float)y4[0] * wv; acc[2][1] += (float)y4[1] * wv;
                acc[2][2] += (float)y4[2] * wv; acc[2][3] += (float)y4[3] * wv;
            }
            {
                const float wv = d3[reg];
                const half4 y4 = *(const half4*)&ytile[pbF3 + toffF];
                acc[3][0] += (float)y4[0] * wv; acc[3][1] += (float)y4[1] * wv;
                acc[3][2] += (float)y4[2] * wv; acc[3][3] += (float)y4[3] * wv;
            }
        }
    }

    // mt = 3 : only tap 48 real (lane r==0 holds row 48; q==0 output)
    {
        half8 af = *(const half8*)&w2hg[48 * W2ST + q * 8];
        if (r != 0) {
            #pragma unroll
            for (int j = 0; j < 8; ++j) af[j] = (_Float16)0.f;
        }
        __builtin_amdgcn_s_setprio(1);
        f32x4 d0 = __builtin_amdgcn_mfma_f32_16x16x32_f16(af, bfrag0, zero, 0, 0, 0);
        f32x4 d1 = __builtin_amdgcn_mfma_f32_16x16x32_f16(af, bfrag1, zero, 0, 0, 0);
        f32x4 d2 = __builtin_amdgcn_mfma_f32_16x16x32_f16(af, bfrag2, zero, 0, 0, 0);
        f32x4 d3 = __builtin_amdgcn_mfma_f32_16x16x32_f16(af, bfrag3, zero, 0, 0, 0);
        __builtin_amdgcn_s_setprio(0);

        const float bv = b2g[48];
        const int toffF = (48 + 7 * 6) * YPS;        // 90*YPS, uniform
        const bool live = (q == 0);
        {
            float wv = live ? (d0[0] + bv) : 0.f;
            const half4 y4 = *(const half4*)&ytile[pbF0 + toffF];
            acc[0][0] += (float)y4[0] * wv; acc[0][1] += (float)y4[1] * wv;
            acc[0][2] += (float)y4[2] * wv; acc[0][3] += (float)y4[3] * wv;
        }
        {
            float wv = live ? (d1[0] + bv) : 0.f;
            const half4 y4 = *(const half4*)&ytile[pbF1 + toffF];
            acc[1][0] += (float)y4[0] * wv; acc[1][1] += (float)y4[1] * wv;
            acc[1][2] += (float)y4[2] * wv; acc[1][3] += (float)y4[3] * wv;
        }
        {
            float wv = live ? (d2[0] + bv) : 0.f;
            const half4 y4 = *(const half4*)&ytile[pbF2 + toffF];
            acc[2][0] += (float)y4[0] * wv; acc[2][1] += (float)y4[1] * wv;
            acc[2][2] += (float)y4[2] * wv; acc[2][3] += (float)y4[3] * wv;
        }
        {
            float wv = live ? (d3[0] + bv) : 0.f;
            const half4 y4 = *(const half4*)&ytile[pbF3 + toffF];
            acc[3][0] += (float)y4[0] * wv; acc[3][1] += (float)y4[1] * wv;
            acc[3][2] += (float)y4[2] * wv; acc[3][3] += (float)y4[3] * wv;
        }
    }

    #pragma unroll
    for (int nt = 0; nt < 4; ++nt)
        #pragma unroll
        for (int c = 0; c < 4; ++c) {
            float v = acc[nt][c];
            v += __shfl_xor(v, 16);
            v += __shfl_xor(v, 32);
            acc[nt][c] = v;
        }

    size_t ob = ((size_t)(b * C64 + g * GC4) << 14) + pix;
    #pragma unroll
    for (int c = 0; c < 4; ++c) {
        float s0 = (q & 1) ? acc[1][c] : acc[0][c];
        float s1 = (q & 1) ? acc[3][c] : acc[2][c];
        float vv = (q & 2) ? s1 : s0;
        out[ob + ((size_t)c << 14)] = vv;
    }
}

// ======================= fused fallback (round-6, 60.8µs) =======================
#define NCHF 32
#define NSLF 8
#define TSTH 40

__global__ __launch_bounds__(256, 2)
void involution_fused_fb(const float* __restrict__ x, const float* __restrict__ y,
                         const float* __restrict__ w1, const float* __restrict__ b1,
                         const float* __restrict__ gma, const float* __restrict__ bta,
                         const float* __restrict__ mu,  const float* __restrict__ var,
                         const float* __restrict__ w2,  const float* __restrict__ b2,
                         float* __restrict__ out)
{
    __shared__ __align__(16) float    ytile[NPIX * NCHF];
    __shared__ __align__(16) _Float16 t_lds[64 * TSTH];

    const int tid = threadIdx.x;
    const int bx = blockIdx.x, by = blockIdx.y, bz = blockIdx.z;
    const int b = bz >> 1, half = bz & 1;
    const int gh0 = by * TILE, gw0 = bx * TILE;
    const int c0 = half * NCHF;

    for (int li = tid; li < NCHF * NPIX; li += 256) {
        int c    = li / NPIX;
        int pixl = li - c * NPIX;
        int rr   = pixl / HALO;
        int col  = pixl - rr * HALO;
        int grow = gh0 - PAD3 + rr;
        int gcol = gw0 - PAD3 + col;
        float v = 0.f;
        if ((unsigned)grow < 128u && (unsigned)gcol < 128u)
            v = y[((size_t)(b * C64 + c0 + c) << 14) + (grow << 7) + gcol];
        int slot = ((c >> 2) + pixl) & 7;
        ytile[pixl * NCHF + slot * 4 + (c & 3)] = v;
    }

    const int p  = tid & 63;
    const int ph = p >> 3, pw = p & 7;
    const int oq = __builtin_amdgcn_readfirstlane(tid >> 6);
    const int pix = ((gh0 + ph) << 7) + (gw0 + pw);
    {
        float dot[8] = {0,0,0,0,0,0,0,0};
        const float* w1q = w1 + oq * 8 * C64;
        const float* xp  = x + ((size_t)(b * C64) << 14) + pix;
        #pragma unroll 8
        for (int c = 0; c < C64; ++c) {
            float xc = xp[(size_t)c << 14];
            #pragma unroll
            for (int j = 0; j < 8; ++j) dot[j] += w1q[j * C64 + c] * xc;
        }
        _Float16 tv16[8];
        #pragma unroll
        for (int j = 0; j < 8; ++j) {
            int o = oq * 8 + j;
            float sv = gma[o] * rsqrtf(var[o] + EPSV);
            float bb = (b1[o] - mu[o]) * sv + bta[o];
            tv16[j] = (_Float16)fmaxf(dot[j] * sv + bb, 0.f);
        }
        *(half8*)&t_lds[p * TSTH + oq * 8] = *(const half8*)tv16;
    }
    __syncthreads();

    const int q = p >> 4;
    const int r = p & 15;

    half8 bfrag0 = *(const half8*)&t_lds[( 0 + r) * TSTH + q * 8];
    half8 bfrag1 = *(const half8*)&t_lds[(16 + r) * TSTH + q * 8];
    half8 bfrag2 = *(const half8*)&t_lds[(32 + r) * TSTH + q * 8];
    half8 bfrag3 = *(const half8*)&t_lds[(48 + r) * TSTH + q * 8];

    const int pb0 = (0 + (r >> 3)) * HALO + (r & 7);
    const int pb1 = (2 + (r >> 3)) * HALO + (r & 7);
    const int pb2 = (4 + (r >> 3)) * HALO + (r & 7);
    const int pb3 = (6 + (r >> 3)) * HALO + (r & 7);

    const f32x4 zero = {0.f, 0.f, 0.f, 0.f};

    #pragma unroll 1
    for (int lgi = 0; lgi < 2; ++lgi) {
        const int lg = oq * 2 + lgi;
        const int g  = half * NSLF + lg;
        const float* w2g = w2 + g * 49 * CRED;
        const float* b2g = b2 + g * 49;

        float acc[4][4];
        #pragma unroll
        for (int nt = 0; nt < 4; ++nt)
            #pragma unroll
            for (int c = 0; c < 4; ++c) acc[nt][c] = 0.f;

        #pragma clang loop unroll(disable)
        for (int mt = 0; mt < 3; ++mt) {
            half8 af;
            {
                const float* wr = w2g + (mt * 16 + r) * CRED + q * 8;
                float4 wa = *(const float4*)wr;
                float4 wb = *(const float4*)(wr + 4);
                af[0] = (_Float16)wa.x; af[1] = (_Float16)wa.y;
                af[2] = (_Float16)wa.z; af[3] = (_Float16)wa.w;
                af[4] = (_Float16)wb.x; af[5] = (_Float16)wb.y;
                af[6] = (_Float16)wb.z; af[7] = (_Float16)wb.w;
            }
            f32x4 d0 = __builtin_amdgcn_mfma_f32_16x16x32_f16(af, bfrag0, zero, 0, 0, 0);
            f32x4 d1 = __builtin_amdgcn_mfma_f32_16x16x32_f16(af, bfrag1, zero, 0, 0, 0);
            f32x4 d2 = __builtin_amdgcn_mfma_f32_16x16x32_f16(af, bfrag2, zero, 0, 0, 0);
            f32x4 d3 = __builtin_amdgcn_mfma_f32_16x16x32_f16(af, bfrag3, zero, 0, 0, 0);

            #pragma unroll
            for (int reg = 0; reg < 4; ++reg) {
                const int tap = mt * 16 + q * 4 + reg;
                const float bv = b2g[tap];
                const int di = (tap * 9363) >> 16;
                const int tapoff = tap + 7 * di;
                {
                    float wv = d0[reg] + bv;
                    int tp2 = pb0 + tapoff;
                    const float4 y4 = *(const float4*)&ytile[tp2 * NCHF + (((lg + tp2) & 7) << 2)];
                    acc[0][0] += wv * y4.x; acc[0][1] += wv * y4.y;
                    acc[0][2] += wv * y4.z; acc[0][3] += wv * y4.w;
                }
                {
                    float wv = d1[reg] + bv;
                    int tp2 = pb1 + tapoff;
                    const float4 y4 = *(const float4*)&ytile[tp2 * NCHF + (((lg + tp2) & 7) << 2)];
                    acc[1][0] += wv * y4.x; acc[1][1] += wv * y4.y;
                    acc[1][2] += wv * y4.z; acc[1][3] += wv * y4.w;
                }
                {
                    float wv = d2[reg] + bv;
                    int tp2 = pb2 + tapoff;
                    const float4 y4 = *(const float4*)&ytile[tp2 * NCHF + (((lg + tp2) & 7) << 2)];
                    acc[2][0] += wv * y4.x; acc[2][1] += wv * y4.y;
                    acc[2][2] += wv * y4.z; acc[2][3] += wv * y4.w;
                }
                {
                    float wv = d3[reg] + bv;
                    int tp2 = pb3 + tapoff;
                    const float4 y4 = *(const float4*)&ytile[tp2 * NCHF + (((lg + tp2) & 7) << 2)];
                    acc[3][0] += wv * y4.x; acc[3][1] += wv * y4.y;
                    acc[3][2] += wv * y4.z; acc[3][3] += wv * y4.w;
                }
            }
        }

        {
            half8 af;
            #pragma unroll
            for (int j = 0; j < 8; ++j) af[j] = (_Float16)0.f;
            if (r == 0) {
                const float* wr = w2g + 48 * CRED + q * 8;
                float4 wa = *(const float4*)wr;
                float4 wb = *(const float4*)(wr + 4);
                af[0] = (_Float16)wa.x; af[1] = (_Float16)wa.y;
                af[2] = (_Float16)wa.z; af[3] = (_Float16)wa.w;
                af[4] = (_Float16)wb.x; af[5] = (_Float16)wb.y;
                af[6] = (_Float16)wb.z; af[7] = (_Float16)wb.w;
            }
            f32x4 d0 = __builtin_amdgcn_mfma_f32_16x16x32_f16(af, bfrag0, zero, 0, 0, 0);
            f32x4 d1 = __builtin_amdgcn_mfma_f32_16x16x32_f16(af, bfrag1, zero, 0, 0, 0);
            f32x4 d2 = __builtin_amdgcn_mfma_f32_16x16x32_f16(af, bfrag2, zero, 0, 0, 0);
            f32x4 d3 = __builtin_amdgcn_mfma_f32_16x16x32_f16(af, bfrag3, zero, 0, 0, 0);

            const float bv = b2g[48];
            const int tapoff = 48 + 7 * 6;
            const bool live = (q == 0);
            {
                float wv = live ? (d0[0] + bv) : 0.f;
                int tp2 = pb0 + tapoff;
                const float4 y4 = *(const float4*)&ytile[tp2 * NCHF + (((lg + tp2) & 7) << 2)];
                acc[0][0] += wv * y4.x; acc[0][1] += wv * y4.y;
                acc[0][2] += wv * y4.z; acc[0][3] += wv * y4.w;
            }
            {
                float wv = live ? (d1[0] + bv) : 0.f;
                int tp2 = pb1 + tapoff;
                const float4 y4 = *(const float4*)&ytile[tp2 * NCHF + (((lg + tp2) & 7) << 2)];
                acc[1][0] += wv * y4.x; acc[1][1] += wv * y4.y;
                acc[1][2] += wv * y4.z; acc[1][3] += wv * y4.w;
            }
            {
                float wv = live ? (d2[0] + bv) : 0.f;
                int tp2 = pb2 + tapoff;
                const float4 y4 = *(const float4*)&ytile[tp2 * NCHF + (((lg + tp2) & 7) << 2)];
                acc[2][0] += wv * y4.x; acc[2][1] += wv * y4.y;
                acc[2][2] += wv * y4.z; acc[2][3] += wv * y4.w;
            }
            {
                float wv = live ? (d3[0] + bv) : 0.f;
                int tp2 = pb3 + tapoff;
                const float4 y4 = *(const float4*)&ytile[tp2 * NCHF + (((lg + tp2) & 7) << 2)];
                acc[3][0] += wv * y4.x; acc[3][1] += wv * y4.y;
                acc[3][2] += wv * y4.z; acc[3][3] += wv * y4.w;
            }
        }

        #pragma unroll
        for (int nt = 0; nt < 4; ++nt)
            #pragma unroll
            for (int c = 0; c < 4; ++c) {
                float v = acc[nt][c];
                v += __shfl_xor(v, 16);
                v += __shfl_xor(v, 32);
                acc[nt][c] = v;
            }

        size_t ob = ((size_t)(b * C64 + g * GC4) << 14) + pix;
        #pragma unroll
        for (int c = 0; c < 4; ++c) {
            float s0 = (q & 1) ? acc[1][c] : acc[0][c];
            float s1 = (q & 1) ? acc[3][c] : acc[2][c];
            float vv = (q & 2) ? s1 : s0;
            out[ob + ((size_t)c << 14)] = vv;
        }
    }
}

extern "C" void kernel_launch(void* const* d_in, const int* in_sizes, int n_in,
                              void* d_out, int out_size, void* d_ws, size_t ws_size,
                              hipStream_t stream) {
    const float* x   = (const float*)d_in[0];
    const float* y   = (const float*)d_in[1];
    const float* w1  = (const float*)d_in[2];
    const float* b1  = (const float*)d_in[3];
    const float* gma = (const float*)d_in[4];
    const float* bta = (const float*)d_in[5];
    const float* mu  = (const float*)d_in[6];
    const float* var = (const float*)d_in[7];
    const float* w2  = (const float*)d_in[8];
    const float* b2  = (const float*)d_in[9];
    float* out = (float*)d_out;

    const size_t t_bytes = (size_t)4 * 16384 * 32 * sizeof(_Float16);  // 4 MB
    if (ws_size >= t_bytes) {
        _Float16* t = (_Float16*)d_ws;
        hipLaunchKernelGGL(conv1_bn_relu, dim3(1024), dim3(256), 0, stream,
                           x, w1, b1, gma, bta, mu, var, t);
        hipLaunchKernelGGL(invol_agg, dim3(16, 16, 16), dim3(256), 0, stream,
                           y, t, w2, b2, out);
    } else {
        hipLaunchKernelGGL(involution_fused_fb, dim3(16, 16, 8), dim3(256), 0, stream,
                           x, y, w1, b1, gma, bta, mu, var, w2, b2, out);
    }
}

// Round 20
// 42.295 us; speedup vs baseline: 1.1109x; 1.1109x over previous
//
#include <hip/hip_runtime.h>

#define K7   7
#define PAD3 3
#define C64  64
#define CRED 32          // C/2
#define GC4  4
#define EPSV 1e-5f

#define TILE 8                      // 8x8 pixels per block (k2 / fused)
#define HALO 14                     // TILE + K7 - 1
#define NPIX (HALO * HALO)          // 196

typedef _Float16 half8 __attribute__((ext_vector_type(8)));
typedef _Float16 half4 __attribute__((ext_vector_type(4)));
typedef float    f32x4 __attribute__((ext_vector_type(4)));

// ============================= two-kernel path =============================
// ---- kernel 1: conv1 (1x1) + BN(eval) + ReLU -> t[b][pix][32] as f16 ----
__global__ __launch_bounds__(256, 4)
void conv1_bn_relu(const float* __restrict__ x,  const float* __restrict__ w1,
                   const float* __restrict__ b1, const float* __restrict__ gma,
                   const float* __restrict__ bta, const float* __restrict__ mu,
                   const float* __restrict__ var, _Float16* __restrict__ t)
{
    const int tid = threadIdx.x;
    const int p   = tid & 63;
    const int oq  = __builtin_amdgcn_readfirstlane(tid >> 6);
    const int task = blockIdx.x * 64 + p;           // 0 .. 65535
    const int b   = task >> 14;
    const int pix = task & 16383;

    float dot[8] = {0,0,0,0,0,0,0,0};
    const float* w1q = w1 + oq * 8 * C64;
    const float* xp  = x + ((size_t)b << 20) + pix;
    #pragma unroll 8
    for (int c = 0; c < C64; ++c) {
        float xc = xp[(size_t)c << 14];
        #pragma unroll
        for (int j = 0; j < 8; ++j) dot[j] += w1q[j * C64 + c] * xc;
    }
    _Float16 tv[8];
    #pragma unroll
    for (int j = 0; j < 8; ++j) {
        int o = oq * 8 + j;
        float sv = gma[o] * rsqrtf(var[o] + EPSV);
        float bb = (b1[o] - mu[o]) * sv + bta[o];
        tv[j] = (_Float16)fmaxf(dot[j] * sv + bb, 0.f);
    }
    *(half8*)&t[((size_t)((b << 14) + pix)) * 32 + oq * 8] = *(const half8*)tv;
}

// ---- kernel 2: per-pixel dynamic kernels (MFMA) + depthwise aggregation ----
// ROUND-16 CONFIG (measured best, 42.6us total): quarter-channel blocks,
// 1 group/wave, PER-WAVE staging of ytile slice AND w2 group, NO block
// barrier, YPS=20 / W2ST=40 (983K conflicts; 18/36 variant tripled them).
#define NCH2 16                     // y-channels per block (quarter of 64)
#define NSL2 4                      // channel-groups per block (1 per wave)
#define YPS  20                     // ytile per-pixel stride in f16 (40B)
#define W2ST 40                     // w2h row stride in f16 (80B, 16B-aligned)
#define W2G  (49 * W2ST)            // 1960 f16 per group

__global__ __launch_bounds__(256, 4)
void invol_agg(const float* __restrict__ y, const _Float16* __restrict__ t,
               const float* __restrict__ w2, const float* __restrict__ b2,
               float* __restrict__ out)
{
    __shared__ __align__(16) _Float16 ytile[NPIX * YPS];   //  7840 B
    __shared__ __align__(16) _Float16 w2h[NSL2 * W2G];     // 15680 B

    const int tid = threadIdx.x;
    // XCD-aware swizzle: 4096 blocks -> 8 chunks of 512 contiguous tiles
    const int wgid = blockIdx.x + (blockIdx.y << 4) + (blockIdx.z << 8);
    const int swz  = ((wgid & 7) << 9) | (wgid >> 3);
    const int bx = swz & 15, by = (swz >> 4) & 15, bz = swz >> 8;
    const int b = bz >> 2, quarter = bz & 3;
    const int gh0 = by * TILE, gw0 = bx * TILE;
    const int c0 = quarter * NCH2;

    const int p  = tid & 63;
    const int ph = p >> 3, pw = p & 7;
    const int oq = __builtin_amdgcn_readfirstlane(tid >> 6);  // wave = group 0..3
    const int q  = p >> 4, r = p & 15;
    const int pix = ((gh0 + ph) << 7) + (gw0 + pw);

    const int g = quarter * NSL2 + oq;         // global group 0..15

    // --- issue B-fragment loads EARLY: latency hides under staging ---
    const _Float16* tb = t + ((size_t)(b << 14)) * 32;
    const int rr8 = r >> 3, rc = r & 7;
    half8 bfrag0 = *(const half8*)&tb[(size_t)(((gh0 + 0 + rr8) << 7) + gw0 + rc) * 32 + q * 8];
    half8 bfrag1 = *(const half8*)&tb[(size_t)(((gh0 + 2 + rr8) << 7) + gw0 + rc) * 32 + q * 8];
    half8 bfrag2 = *(const half8*)&tb[(size_t)(((gh0 + 4 + rr8) << 7) + gw0 + rc) * 32 + q * 8];
    half8 bfrag3 = *(const half8*)&tb[(size_t)(((gh0 + 6 + rr8) << 7) + gw0 + rc) * 32 + q * 8];

    // --- per-wave y halo staging: wave oq stages ONLY its 4 channels ---
    #pragma unroll
    for (int i = 0; i < 4; ++i) {
        int pixl = p + i * 64;                 // 0..195
        if (pixl < NPIX) {
            int rr   = pixl / HALO;
            int col  = pixl - rr * HALO;
            int grow = gh0 - PAD3 + rr;
            int gcol = gw0 - PAD3 + col;
            half4 v = {(_Float16)0.f, (_Float16)0.f, (_Float16)0.f, (_Float16)0.f};
            if ((unsigned)grow < 128u && (unsigned)gcol < 128u) {
                const float* yp = y + ((size_t)(b * C64 + c0 + oq * 4) << 14) + (grow << 7) + gcol;
                v[0] = (_Float16)yp[0];
                v[1] = (_Float16)yp[1 << 14];
                v[2] = (_Float16)yp[2 << 14];
                v[3] = (_Float16)yp[3 << 14];
            }
            *(half4*)&ytile[pixl * YPS + oq * 4] = v;
        }
    }

    // --- per-wave w2 staging: wave oq stages ONLY its group ---
    #pragma unroll
    for (int i = 0; i < 7; ++i) {
        int u = p + i * 64;                    // 0..391 (49 rows x 8 half4-units)
        if (u < 392) {
            int row = u >> 3;
            int k4  = (u & 7) << 2;
            const float4 w4 = *(const float4*)&w2[((g * 49 + row) << 5) + k4];
            half4 h;
            h[0] = (_Float16)w4.x; h[1] = (_Float16)w4.y;
            h[2] = (_Float16)w4.z; h[3] = (_Float16)w4.w;
            *(half4*)&w2h[oq * W2G + row * W2ST + k4] = h;
        }
    }
    // NO __syncthreads(): each wave reads only what it wrote; the compiler's
    // lgkmcnt wait before the first dependent ds_read is the only sync needed.

    // per-lane f16-index bases into ytile: tp2*YPS + oq*4
    const int pbF0 = ((0 + rr8) * HALO + rc) * YPS + oq * 4;
    const int pbF1 = ((2 + rr8) * HALO + rc) * YPS + oq * 4;
    const int pbF2 = ((4 + rr8) * HALO + rc) * YPS + oq * 4;
    const int pbF3 = ((6 + rr8) * HALO + rc) * YPS + oq * 4;

    const f32x4 zero = {0.f, 0.f, 0.f, 0.f};

    const float* b2g = b2 + g * 49;
    const _Float16* w2hg = w2h + oq * W2G;     // wave-uniform base

    float acc[4][4];
    #pragma unroll
    for (int nt = 0; nt < 4; ++nt)
        #pragma unroll
        for (int c = 0; c < 4; ++c) acc[nt][c] = 0.f;

    // mt = 0..2 : rolled (liveness cap); A-frag from LDS, bias as C-init
    #pragma clang loop unroll(disable)
    for (int mt = 0; mt < 3; ++mt) {
        const half8 af = *(const half8*)&w2hg[(mt * 16 + r) * W2ST + q * 8];
        const int bi = mt * 16 + q * 4;
        const f32x4 cb = { b2g[bi+0], b2g[bi+1], b2g[bi+2], b2g[bi+3] };

        f32x4 d0 = __builtin_amdgcn_mfma_f32_16x16x32_f16(af, bfrag0, cb, 0, 0, 0);
        f32x4 d1 = __builtin_amdgcn_mfma_f32_16x16x32_f16(af, bfrag1, cb, 0, 0, 0);
        f32x4 d2 = __builtin_amdgcn_mfma_f32_16x16x32_f16(af, bfrag2, cb, 0, 0, 0);
        f32x4 d3 = __builtin_amdgcn_mfma_f32_16x16x32_f16(af, bfrag3, cb, 0, 0, 0);

        #pragma unroll
        for (int reg = 0; reg < 4; ++reg) {          // MUST stay fully unrolled
            const int tap = mt * 16 + q * 4 + reg;   // lane's tap, < 49
            const int di = (tap * 9363) >> 16;       // tap / 7
            const int toffF = (tap + 7 * di) * YPS;  // (di*14 + dj) * YPS
            {
                const float wv = d0[reg];
                const half4 y4 = *(const half4*)&ytile[pbF0 + toffF];
                acc[0][0] += (float)y4[0] * wv; acc[0][1] += (float)y4[1] * wv;
                acc[0][2] += (float)y4[2] * wv; acc[0][3] += (float)y4[3] * wv;
            }
            {
                const float wv = d1[reg];
                const half4 y4 = *(const half4*)&ytile[pbF1 + toffF];
                acc[1][0] += (float)y4[0] * wv; acc[1][1] += (float)y4[1] * wv;
                acc[1][2] += (float)y4[2] * wv; acc[1][3] += (float)y4[3] * wv;
            }
            {
                const float wv = d2[reg];
                const half4 y4 = *(const half4*)&ytile[pbF2 + toffF];
                acc[2][0] += (float)y4[0] * wv; acc[2][1] += (float)y4[1] * wv;
                acc[2][2] += (float)y4[2] * wv; acc[2][3] += (float)y4[3] * wv;
            }
            {
                const float wv = d3[reg];
                const half4 y4 = *(const half4*)&ytile[pbF3 + toffF];
                acc[3][0] += (float)y4[0] * wv; acc[3][1] += (float)y4[1] * wv;
                acc[3][2] += (float)y4[2] * wv; acc[3][3] += (float)y4[3] * wv;
            }
        }
    }

    // mt = 3 : only tap 48 real (lane r==0 holds row 48; q==0 output)
    {
        half8 af = *(const half8*)&w2hg[48 * W2ST + q * 8];
        if (r != 0) {
            #pragma unroll
            for (int j = 0; j < 8; ++j) af[j] = (_Float16)0.f;
        }
        f32x4 d0 = __builtin_amdgcn_mfma_f32_16x16x32_f16(af, bfrag0, zero, 0, 0, 0);
        f32x4 d1 = __builtin_amdgcn_mfma_f32_16x16x32_f16(af, bfrag1, zero, 0, 0, 0);
        f32x4 d2 = __builtin_amdgcn_mfma_f32_16x16x32_f16(af, bfrag2, zero, 0, 0, 0);
        f32x4 d3 = __builtin_amdgcn_mfma_f32_16x16x32_f16(af, bfrag3, zero, 0, 0, 0);

        const float bv = b2g[48];
        const int toffF = (48 + 7 * 6) * YPS;        // 90*YPS, uniform
        const bool live = (q == 0);
        {
            float wv = live ? (d0[0] + bv) : 0.f;
            const half4 y4 = *(const half4*)&ytile[pbF0 + toffF];
            acc[0][0] += (float)y4[0] * wv; acc[0][1] += (float)y4[1] * wv;
            acc[0][2] += (float)y4[2] * wv; acc[0][3] += (float)y4[3] * wv;
        }
        {
            float wv = live ? (d1[0] + bv) : 0.f;
            const half4 y4 = *(const half4*)&ytile[pbF1 + toffF];
            acc[1][0] += (float)y4[0] * wv; acc[1][1] += (float)y4[1] * wv;
            acc[1][2] += (float)y4[2] * wv; acc[1][3] += (float)y4[3] * wv;
        }
        {
            float wv = live ? (d2[0] + bv) : 0.f;
            const half4 y4 = *(const half4*)&ytile[pbF2 + toffF];
            acc[2][0] += (float)y4[0] * wv; acc[2][1] += (float)y4[1] * wv;
            acc[2][2] += (float)y4[2] * wv; acc[2][3] += (float)y4[3] * wv;
        }
        {
            float wv = live ? (d3[0] + bv) : 0.f;
            const half4 y4 = *(const half4*)&ytile[pbF3 + toffF];
            acc[3][0] += (float)y4[0] * wv; acc[3][1] += (float)y4[1] * wv;
            acc[3][2] += (float)y4[2] * wv; acc[3][3] += (float)y4[3] * wv;
        }
    }

    #pragma unroll
    for (int nt = 0; nt < 4; ++nt)
        #pragma unroll
        for (int c = 0; c < 4; ++c) {
            float v = acc[nt][c];
            v += __shfl_xor(v, 16);
            v += __shfl_xor(v, 32);
            acc[nt][c] = v;
        }

    size_t ob = ((size_t)(b * C64 + g * GC4) << 14) + pix;
    #pragma unroll
    for (int c = 0; c < 4; ++c) {
        float s0 = (q & 1) ? acc[1][c] : acc[0][c];
        float s1 = (q & 1) ? acc[3][c] : acc[2][c];
        float vv = (q & 2) ? s1 : s0;
        out[ob + ((size_t)c << 14)] = vv;
    }
}

// ======================= fused fallback (round-6, 60.8µs) =======================
#define NCHF 32
#define NSLF 8
#define TSTH 40

__global__ __launch_bounds__(256, 2)
void involution_fused_fb(const float* __restrict__ x, const float* __restrict__ y,
                         const float* __restrict__ w1, const float* __restrict__ b1,
                         const float* __restrict__ gma, const float* __restrict__ bta,
                         const float* __restrict__ mu,  const float* __restrict__ var,
                         const float* __restrict__ w2,  const float* __restrict__ b2,
                         float* __restrict__ out)
{
    __shared__ __align__(16) float    ytile[NPIX * NCHF];
    __shared__ __align__(16) _Float16 t_lds[64 * TSTH];

    const int tid = threadIdx.x;
    const int bx = blockIdx.x, by = blockIdx.y, bz = blockIdx.z;
    const int b = bz >> 1, half = bz & 1;
    const int gh0 = by * TILE, gw0 = bx * TILE;
    const int c0 = half * NCHF;

    for (int li = tid; li < NCHF * NPIX; li += 256) {
        int c    = li / NPIX;
        int pixl = li - c * NPIX;
        int rr   = pixl / HALO;
        int col  = pixl - rr * HALO;
        int grow = gh0 - PAD3 + rr;
        int gcol = gw0 - PAD3 + col;
        float v = 0.f;
        if ((unsigned)grow < 128u && (unsigned)gcol < 128u)
            v = y[((size_t)(b * C64 + c0 + c) << 14) + (grow << 7) + gcol];
        int slot = ((c >> 2) + pixl) & 7;
        ytile[pixl * NCHF + slot * 4 + (c & 3)] = v;
    }

    const int p  = tid & 63;
    const int ph = p >> 3, pw = p & 7;
    const int oq = __builtin_amdgcn_readfirstlane(tid >> 6);
    const int pix = ((gh0 + ph) << 7) + (gw0 + pw);
    {
        float dot[8] = {0,0,0,0,0,0,0,0};
        const float* w1q = w1 + oq * 8 * C64;
        const float* xp  = x + ((size_t)(b * C64) << 14) + pix;
        #pragma unroll 8
        for (int c = 0; c < C64; ++c) {
            float xc = xp[(size_t)c << 14];
            #pragma unroll
            for (int j = 0; j < 8; ++j) dot[j] += w1q[j * C64 + c] * xc;
        }
        _Float16 tv16[8];
        #pragma unroll
        for (int j = 0; j < 8; ++j) {
            int o = oq * 8 + j;
            float sv = gma[o] * rsqrtf(var[o] + EPSV);
            float bb = (b1[o] - mu[o]) * sv + bta[o];
            tv16[j] = (_Float16)fmaxf(dot[j] * sv + bb, 0.f);
        }
        *(half8*)&t_lds[p * TSTH + oq * 8] = *(const half8*)tv16;
    }
    __syncthreads();

    const int q = p >> 4;
    const int r = p & 15;

    half8 bfrag0 = *(const half8*)&t_lds[( 0 + r) * TSTH + q * 8];
    half8 bfrag1 = *(const half8*)&t_lds[(16 + r) * TSTH + q * 8];
    half8 bfrag2 = *(const half8*)&t_lds[(32 + r) * TSTH + q * 8];
    half8 bfrag3 = *(const half8*)&t_lds[(48 + r) * TSTH + q * 8];

    const int pb0 = (0 + (r >> 3)) * HALO + (r & 7);
    const int pb1 = (2 + (r >> 3)) * HALO + (r & 7);
    const int pb2 = (4 + (r >> 3)) * HALO + (r & 7);
    const int pb3 = (6 + (r >> 3)) * HALO + (r & 7);

    const f32x4 zero = {0.f, 0.f, 0.f, 0.f};

    #pragma unroll 1
    for (int lgi = 0; lgi < 2; ++lgi) {
        const int lg = oq * 2 + lgi;
        const int g  = half * NSLF + lg;
        const float* w2g = w2 + g * 49 * CRED;
        const float* b2g = b2 + g * 49;

        float acc[4][4];
        #pragma unroll
        for (int nt = 0; nt < 4; ++nt)
            #pragma unroll
            for (int c = 0; c < 4; ++c) acc[nt][c] = 0.f;

        #pragma clang loop unroll(disable)
        for (int mt = 0; mt < 3; ++mt) {
            half8 af;
            {
                const float* wr = w2g + (mt * 16 + r) * CRED + q * 8;
                float4 wa = *(const float4*)wr;
                float4 wb = *(const float4*)(wr + 4);
                af[0] = (_Float16)wa.x; af[1] = (_Float16)wa.y;
                af[2] = (_Float16)wa.z; af[3] = (_Float16)wa.w;
                af[4] = (_Float16)wb.x; af[5] = (_Float16)wb.y;
                af[6] = (_Float16)wb.z; af[7] = (_Float16)wb.w;
            }
            f32x4 d0 = __builtin_amdgcn_mfma_f32_16x16x32_f16(af, bfrag0, zero, 0, 0, 0);
            f32x4 d1 = __builtin_amdgcn_mfma_f32_16x16x32_f16(af, bfrag1, zero, 0, 0, 0);
            f32x4 d2 = __builtin_amdgcn_mfma_f32_16x16x32_f16(af, bfrag2, zero, 0, 0, 0);
            f32x4 d3 = __builtin_amdgcn_mfma_f32_16x16x32_f16(af, bfrag3, zero, 0, 0, 0);

            #pragma unroll
            for (int reg = 0; reg < 4; ++reg) {
                const int tap = mt * 16 + q * 4 + reg;
                const float bv = b2g[tap];
                const int di = (tap * 9363) >> 16;
                const int tapoff = tap + 7 * di;
                {
                    float wv = d0[reg] + bv;
                    int tp2 = pb0 + tapoff;
                    const float4 y4 = *(const float4*)&ytile[tp2 * NCHF + (((lg + tp2) & 7) << 2)];
                    acc[0][0] += wv * y4.x; acc[0][1] += wv * y4.y;
                    acc[0][2] += wv * y4.z; acc[0][3] += wv * y4.w;
                }
                {
                    float wv = d1[reg] + bv;
                    int tp2 = pb1 + tapoff;
                    const float4 y4 = *(const float4*)&ytile[tp2 * NCHF + (((lg + tp2) & 7) << 2)];
                    acc[1][0] += wv * y4.x; acc[1][1] += wv * y4.y;
                    acc[1][2] += wv * y4.z; acc[1][3] += wv * y4.w;
                }
                {
                    float wv = d2[reg] + bv;
                    int tp2 = pb2 + tapoff;
                    const float4 y4 = *(const float4*)&ytile[tp2 * NCHF + (((lg + tp2) & 7) << 2)];
                    acc[2][0] += wv * y4.x; acc[2][1] += wv * y4.y;
                    acc[2][2] += wv * y4.z; acc[2][3] += wv * y4.w;
                }
                {
                    float wv = d3[reg] + bv;
                    int tp2 = pb3 + tapoff;
                    const float4 y4 = *(const float4*)&ytile[tp2 * NCHF + (((lg + tp2) & 7) << 2)];
                    acc[3][0] += wv * y4.x; acc[3][1] += wv * y4.y;
                    acc[3][2] += wv * y4.z; acc[3][3] += wv * y4.w;
                }
            }
        }

        {
            half8 af;
            #pragma unroll
            for (int j = 0; j < 8; ++j) af[j] = (_Float16)0.f;
            if (r == 0) {
                const float* wr = w2g + 48 * CRED + q * 8;
                float4 wa = *(const float4*)wr;
                float4 wb = *(const float4*)(wr + 4);
                af[0] = (_Float16)wa.x; af[1] = (_Float16)wa.y;
                af[2] = (_Float16)wa.z; af[3] = (_Float16)wa.w;
                af[4] = (_Float16)wb.x; af[5] = (_Float16)wb.y;
                af[6] = (_Float16)wb.z; af[7] = (_Float16)wb.w;
            }
            f32x4 d0 = __builtin_amdgcn_mfma_f32_16x16x32_f16(af, bfrag0, zero, 0, 0, 0);
            f32x4 d1 = __builtin_amdgcn_mfma_f32_16x16x32_f16(af, bfrag1, zero, 0, 0, 0);
            f32x4 d2 = __builtin_amdgcn_mfma_f32_16x16x32_f16(af, bfrag2, zero, 0, 0, 0);
            f32x4 d3 = __builtin_amdgcn_mfma_f32_16x16x32_f16(af, bfrag3, zero, 0, 0, 0);

            const float bv = b2g[48];
            const int tapoff = 48 + 7 * 6;
            const bool live = (q == 0);
            {
                float wv = live ? (d0[0] + bv) : 0.f;
                int tp2 = pb0 + tapoff;
                const float4 y4 = *(const float4*)&ytile[tp2 * NCHF + (((lg + tp2) & 7) << 2)];
                acc[0][0] += wv * y4.x; acc[0][1] += wv * y4.y;
                acc[0][2] += wv * y4.z; acc[0][3] += wv * y4.w;
            }
            {
                float wv = live ? (d1[0] + bv) : 0.f;
                int tp2 = pb1 + tapoff;
                const float4 y4 = *(const float4*)&ytile[tp2 * NCHF + (((lg + tp2) & 7) << 2)];
                acc[1][0] += wv * y4.x; acc[1][1] += wv * y4.y;
                acc[1][2] += wv * y4.z; acc[1][3] += wv * y4.w;
            }
            {
                float wv = live ? (d2[0] + bv) : 0.f;
                int tp2 = pb2 + tapoff;
                const float4 y4 = *(const float4*)&ytile[tp2 * NCHF + (((lg + tp2) & 7) << 2)];
                acc[2][0] += wv * y4.x; acc[2][1] += wv * y4.y;
                acc[2][2] += wv * y4.z; acc[2][3] += wv * y4.w;
            }
            {
                float wv = live ? (d3[0] + bv) : 0.f;
                int tp2 = pb3 + tapoff;
                const float4 y4 = *(const float4*)&ytile[tp2 * NCHF + (((lg + tp2) & 7) << 2)];
                acc[3][0] += wv * y4.x; acc[3][1] += wv * y4.y;
                acc[3][2] += wv * y4.z; acc[3][3] += wv * y4.w;
            }
        }

        #pragma unroll
        for (int nt = 0; nt < 4; ++nt)
            #pragma unroll
            for (int c = 0; c < 4; ++c) {
                float v = acc[nt][c];
                v += __shfl_xor(v, 16);
                v += __shfl_xor(v, 32);
                acc[nt][c] = v;
            }

        size_t ob = ((size_t)(b * C64 + g * GC4) << 14) + pix;
        #pragma unroll
        for (int c = 0; c < 4; ++c) {
            float s0 = (q & 1) ? acc[1][c] : acc[0][c];
            float s1 = (q & 1) ? acc[3][c] : acc[2][c];
            float vv = (q & 2) ? s1 : s0;
            out[ob + ((size_t)c << 14)] = vv;
        }
    }
}

extern "C" void kernel_launch(void* const* d_in, const int* in_sizes, int n_in,
                              void* d_out, int out_size, void* d_ws, size_t ws_size,
                              hipStream_t stream) {
    const float* x   = (const float*)d_in[0];
    const float* y   = (const float*)d_in[1];
    const float* w1  = (const float*)d_in[2];
    const float* b1  = (const float*)d_in[3];
    const float* gma = (const float*)d_in[4];
    const float* bta = (const float*)d_in[5];
    const float* mu  = (const float*)d_in[6];
    const float* var = (const float*)d_in[7];
    const float* w2  = (const float*)d_in[8];
    const float* b2  = (const float*)d_in[9];
    float* out = (float*)d_out;

    const size_t t_bytes = (size_t)4 * 16384 * 32 * sizeof(_Float16);  // 4 MB
    if (ws_size >= t_bytes) {
        _Float16* t = (_Float16*)d_ws;
        hipLaunchKernelGGL(conv1_bn_relu, dim3(1024), dim3(256), 0, stream,
                           x, w1, b1, gma, bta, mu, var, t);
        hipLaunchKernelGGL(invol_agg, dim3(16, 16, 16), dim3(256), 0, stream,
                           y, t, w2, b2, out);
    } else {
        hipLaunchKernelGGL(involution_fused_fb, dim3(16, 16, 8), dim3(256), 0, stream,
                           x, y, w1, b1, gma, bta, mu, var, w2, b2, out);
    }
}